// Round 11
// baseline (222.674 us; speedup 1.0000x reference)
//
#include <hip/hip_runtime.h>
#include <hip/hip_bf16.h>
#include <hip/hip_fp16.h>

typedef unsigned short u16;
typedef __attribute__((ext_vector_type(8))) short short8;
typedef __attribute__((ext_vector_type(8))) u16 u16x8;
typedef __attribute__((ext_vector_type(4))) u16 u16x4;
typedef __attribute__((ext_vector_type(8))) _Float16 half8;
typedef __attribute__((ext_vector_type(4))) float f32x4;

#define NB 8
#define TQn 1024
#define TKn 4096
#define DINn 1024
#define DOUTn 256
#define NROWS (NB * TQn)
#define NKB (TKn / 128)
#define NKC 8           // split-K factor for PV
#define KCH (TKn / NKC) // 512
#define EXPSHIFT 40.0f
#define LP 40   // LDS row stride (u16) = 80 B: 16B-aligned rows

#define DEV static __device__ __forceinline__

DEV u16 f2bf(float x) {
    __hip_bfloat16 h = __float2bfloat16(x);
    return *reinterpret_cast<u16*>(&h);
}
DEV float bf2f(u16 u) {
    __hip_bfloat16 h;
    *reinterpret_cast<u16*>(&h) = u;
    return __bfloat162float(h);
}
DEV void split2(float x, u16& hi, u16& lo) {
    u16 h = f2bf(x);
    float hf = bf2f(h);
    hi = h;
    lo = f2bf(x - hf);
}
DEV void split4(const float4 v, u16x4& h, u16x4& l) {
    u16 h0, l0, h1, l1, h2, l2, h3, l3;
    split2(v.x, h0, l0);
    split2(v.y, h1, l1);
    split2(v.z, h2, l2);
    split2(v.w, h3, l3);
    h = (u16x4){h0, h1, h2, h3};
    l = (u16x4){l0, l1, l2, l3};
}
DEV short8 ld8s(const u16* p) { return *reinterpret_cast<const short8*>(p); }
DEV half8 ld8h(const u16* p) { return *reinterpret_cast<const half8*>(p); }
DEV void st8(u16* p, u16x8 v) { *reinterpret_cast<u16x8*>(p) = v; }

// ---------------------------------------------------------------------------
// Kernel 1: emb preprocessing.
//   embT [B][DOUT][TK] fp16 (transposed, for PV)
//   ehi/elo [B][TK][DOUT] bf16 hi/lo split (for scores B-staging)
// ---------------------------------------------------------------------------
__global__ __launch_bounds__(256) void k_embT(const float* __restrict__ emb,
                                              _Float16* __restrict__ embT,
                                              u16* __restrict__ ehi,
                                              u16* __restrict__ elo) {
    __shared__ float tile[64][65];
    const int b = blockIdx.z;
    const int k0 = blockIdx.x * 64;
    const int o0 = blockIdx.y * 64;
    const int t = threadIdx.x;
    const int c = t & 63;
    const int r0 = t >> 6;
#pragma unroll
    for (int i = 0; i < 16; i++) {
        int r = r0 + i * 4;
        size_t idx = ((size_t)b * TKn + k0 + r) * DOUTn + o0 + c;
        float v = emb[idx];
        tile[c][r] = v;
        u16 h, l;
        split2(v, h, l);
        ehi[idx] = h;
        elo[idx] = l;
    }
    __syncthreads();
#pragma unroll
    for (int i = 0; i < 16; i++) {
        int r = r0 + i * 4;
        embT[((size_t)b * DOUTn + o0 + r) * TKn + k0 + c] = (_Float16)tile[r][c];
    }
}

// ---------------------------------------------------------------------------
// Kernel 2: linear  decsmall = dec @ W^T + b, split into hi/lo bf16
// ---------------------------------------------------------------------------
__global__ __launch_bounds__(256) void k_linear(const float* __restrict__ dec,
                                                const float* __restrict__ W,
                                                const float* __restrict__ bias,
                                                u16* __restrict__ ds_hi,
                                                u16* __restrict__ ds_lo) {
    __shared__ u16 sAh[128][LP], sAl[128][LP], sBh[64][LP], sBl[64][LP];
    const int t = threadIdx.x;
    const int m0 = blockIdx.x * 128;
    const int n0 = blockIdx.y * 64;
    const int w = t >> 6, lane = t & 63;
    const int wr = w >> 1, wc = w & 1;
    const int lr = lane & 15, g = lane >> 4, kg8 = g * 8;

    f32x4 acc[4][2];
#pragma unroll
    for (int m = 0; m < 4; m++)
#pragma unroll
        for (int n = 0; n < 2; n++) acc[m][n] = (f32x4){0.f, 0.f, 0.f, 0.f};

    for (int k0 = 0; k0 < DINn; k0 += 32) {
        __syncthreads();
#pragma unroll
        for (int i = 0; i < 4; i++) {
            int f = i * 256 + t;
            int row = f >> 3, c4 = (f & 7) * 4;
            const float4 v = *reinterpret_cast<const float4*>(
                dec + (size_t)(m0 + row) * DINn + k0 + c4);
            u16x4 h, l;
            split4(v, h, l);
            *reinterpret_cast<u16x4*>(&sAh[row][c4]) = h;
            *reinterpret_cast<u16x4*>(&sAl[row][c4]) = l;
        }
#pragma unroll
        for (int i = 0; i < 2; i++) {
            int f = i * 256 + t;
            int row = f >> 3, c4 = (f & 7) * 4;
            const float4 v = *reinterpret_cast<const float4*>(
                W + (size_t)(n0 + row) * DINn + k0 + c4);
            u16x4 h, l;
            split4(v, h, l);
            *reinterpret_cast<u16x4*>(&sBh[row][c4]) = h;
            *reinterpret_cast<u16x4*>(&sBl[row][c4]) = l;
        }
        __syncthreads();
        short8 ah[4], al[4], bh[2], bl[2];
#pragma unroll
        for (int m = 0; m < 4; m++) {
            int row = wr * 64 + m * 16 + lr;
            ah[m] = ld8s(&sAh[row][kg8]);
            al[m] = ld8s(&sAl[row][kg8]);
        }
#pragma unroll
        for (int n = 0; n < 2; n++) {
            int row = wc * 32 + n * 16 + lr;
            bh[n] = ld8s(&sBh[row][kg8]);
            bl[n] = ld8s(&sBl[row][kg8]);
        }
#pragma unroll
        for (int m = 0; m < 4; m++)
#pragma unroll
            for (int n = 0; n < 2; n++) {
                acc[m][n] = __builtin_amdgcn_mfma_f32_16x16x32_bf16(ah[m], bh[n], acc[m][n], 0, 0, 0);
                acc[m][n] = __builtin_amdgcn_mfma_f32_16x16x32_bf16(ah[m], bl[n], acc[m][n], 0, 0, 0);
                acc[m][n] = __builtin_amdgcn_mfma_f32_16x16x32_bf16(al[m], bh[n], acc[m][n], 0, 0, 0);
            }
    }
#pragma unroll
    for (int m = 0; m < 4; m++) {
#pragma unroll
        for (int n = 0; n < 2; n++) {
            int colg = n0 + wc * 32 + n * 16 + lr;
            float bv = bias[colg];
#pragma unroll
            for (int r = 0; r < 4; r++) {
                int rowg = m0 + wr * 64 + m * 16 + g * 4 + r;
                float v = acc[m][n][r] + bv;
                u16 h, l;
                split2(v, h, l);
                ds_hi[(size_t)rowg * DOUTn + colg] = h;
                ds_lo[(size_t)rowg * DOUTn + colg] = l;
            }
        }
    }
}

// ---------------------------------------------------------------------------
// Kernel 3: scores GEMM (split 3-MFMA) + mask + p_u = exp(s - 40) nt-write
//           + per-row partial sums -> partsum[kb][row]
// A and B staged from PRE-SPLIT bf16 arrays: pure b128 copies, no VALU split,
// uniform bank pattern (20r mod 32 cycles all 4-bank groups).
// ---------------------------------------------------------------------------
__global__ __launch_bounds__(256) void k_scores_exp(const u16* __restrict__ ds_hi,
                                                    const u16* __restrict__ ds_lo,
                                                    const u16* __restrict__ ehi,
                                                    const u16* __restrict__ elo,
                                                    const int* __restrict__ emask,
                                                    float* __restrict__ attn,
                                                    float* __restrict__ partsum) {
    __shared__ u16 sAh[128][LP], sAl[128][LP], sBh[128][LP], sBl[128][LP];
    __shared__ float sSum[2][128];
    const int t = threadIdx.x;
    const int flat = blockIdx.x + 8 * (blockIdx.y + 32 * blockIdx.z);
    const int b = flat & 7;
    const int rest = flat >> 3;
    const int kb = rest & 31;
    const int q0 = (rest >> 5) * 128;
    const int kb0 = kb * 128;
    const int w = t >> 6, lane = t & 63;
    const int wr = w >> 1, wc = w & 1;
    const int lr = lane & 15, g = lane >> 4, kg8 = g * 8;

    f32x4 acc[4][4];
#pragma unroll
    for (int m = 0; m < 4; m++)
#pragma unroll
        for (int n = 0; n < 4; n++) acc[m][n] = (f32x4){0.f, 0.f, 0.f, 0.f};

    for (int o0 = 0; o0 < DOUTn; o0 += 32) {
        __syncthreads();
        // stage A: decsmall hi/lo bf16 128x32 (b128 copies)
#pragma unroll
        for (int i = 0; i < 2; i++) {
            int f8 = i * 256 + t;
            int row = f8 >> 2, c8 = (f8 & 3) * 8;
            size_t src = (size_t)(b * TQn + q0 + row) * DOUTn + o0 + c8;
            st8(&sAh[row][c8], *reinterpret_cast<const u16x8*>(ds_hi + src));
            st8(&sAl[row][c8], *reinterpret_cast<const u16x8*>(ds_lo + src));
        }
        // stage B: emb hi/lo bf16 128x32 (b128 copies from pre-split)
#pragma unroll
        for (int i = 0; i < 2; i++) {
            int f8 = i * 256 + t;
            int row = f8 >> 2, c8 = (f8 & 3) * 8;
            size_t src = (size_t)(b * TKn + kb0 + row) * DOUTn + o0 + c8;
            st8(&sBh[row][c8], *reinterpret_cast<const u16x8*>(ehi + src));
            st8(&sBl[row][c8], *reinterpret_cast<const u16x8*>(elo + src));
        }
        __syncthreads();
        short8 ah[4], al[4], bh[4], bl[4];
#pragma unroll
        for (int m = 0; m < 4; m++) {
            int row = wr * 64 + m * 16 + lr;
            ah[m] = ld8s(&sAh[row][kg8]);
            al[m] = ld8s(&sAl[row][kg8]);
        }
#pragma unroll
        for (int n = 0; n < 4; n++) {
            int row = wc * 64 + n * 16 + lr;
            bh[n] = ld8s(&sBh[row][kg8]);
            bl[n] = ld8s(&sBl[row][kg8]);
        }
#pragma unroll
        for (int m = 0; m < 4; m++)
#pragma unroll
            for (int n = 0; n < 4; n++) {
                acc[m][n] = __builtin_amdgcn_mfma_f32_16x16x32_bf16(ah[m], bh[n], acc[m][n], 0, 0, 0);
                acc[m][n] = __builtin_amdgcn_mfma_f32_16x16x32_bf16(ah[m], bl[n], acc[m][n], 0, 0, 0);
                acc[m][n] = __builtin_amdgcn_mfma_f32_16x16x32_bf16(al[m], bh[n], acc[m][n], 0, 0, 0);
            }
    }
    const int* em = emask + (size_t)b * TKn;
    float* pout = attn + ((size_t)(b * TQn + q0)) * TKn + kb0;
    float rowAcc[4][4];
#pragma unroll
    for (int m = 0; m < 4; m++)
#pragma unroll
        for (int r = 0; r < 4; r++) rowAcc[m][r] = 0.f;

#pragma unroll
    for (int n = 0; n < 4; n++) {
        int colL = wc * 64 + n * 16 + lr;
        int mk = em[kb0 + colL];
#pragma unroll
        for (int m = 0; m < 4; m++) {
#pragma unroll
            for (int r = 0; r < 4; r++) {
                int rowL = wr * 64 + m * 16 + g * 4 + r;
                float p = mk ? __expf(acc[m][n][r] - EXPSHIFT) : 0.f;
                __builtin_nontemporal_store(p, &pout[(size_t)rowL * TKn + colL]);
                rowAcc[m][r] += p;
            }
        }
    }
#pragma unroll
    for (int m = 0; m < 4; m++) {
#pragma unroll
        for (int r = 0; r < 4; r++) {
            float v = rowAcc[m][r];
            v += __shfl_xor(v, 1);
            v += __shfl_xor(v, 2);
            v += __shfl_xor(v, 4);
            v += __shfl_xor(v, 8);
            if (lr == 0) sSum[wc][wr * 64 + m * 16 + g * 4 + r] = v;
        }
    }
    __syncthreads();
    if (t < 128) {
        partsum[(size_t)kb * NROWS + (size_t)b * TQn + q0 + t] =
            sSum[0][t] + sSum[1][t];
    }
}

// ---------------------------------------------------------------------------
// Kernel 4: inv_sum[row] = 1 / sum_kb partsum[kb][row]
// ---------------------------------------------------------------------------
__global__ __launch_bounds__(256) void k_rowsum(const float* __restrict__ partsum,
                                                float* __restrict__ inv_sum) {
    int row = blockIdx.x * 256 + threadIdx.x;
    float s = 0.f;
#pragma unroll
    for (int kb = 0; kb < NKB; kb++) s += partsum[(size_t)kb * NROWS + row];
    inv_sum[row] = 1.0f / s;
}

// ---------------------------------------------------------------------------
// Kernel 5: PV GEMM + fused attn normalize write-back.
// 128 q x 256 o per block, split-K x8 (K-chunk 512, NIT=16, KT=32).
// 512 threads = 8 waves (2 q-halves x 4 o-quarters), 16 MFMA/wave/iter.
// Double-buffered LDS, reg prefetch, lgkm-only raw barrier.
// ---------------------------------------------------------------------------
__global__ __launch_bounds__(512, 4) void k_pv8(float* __restrict__ attn,
                                                const _Float16* __restrict__ embT,
                                                const float* __restrict__ inv_sum,
                                                float* __restrict__ partial) {
    __shared__ u16 sA[2][128][LP];   // 20.5 KB
    __shared__ u16 sB[2][256][LP];   // 41 KB
    __shared__ float sInv[128];
    const int t = threadIdx.x;
    const int flat = blockIdx.x;      // 0..511
    const int b = flat & 7;
    const int rest = flat >> 3;       // 0..63
    const int kc = rest & 7;
    const int q0 = (rest >> 3) * 128;
    const int w = t >> 6, lane = t & 63;
    const int lr = lane & 15, g = lane >> 4, kg8 = g * 8;
    const int wr = w >> 2, wc = w & 3;
    const int kbase = kc * KCH;
    const size_t rowBase = (size_t)b * TQn + q0;
    const u16* ebt = reinterpret_cast<const u16*>(embT);

    if (t < 128) sInv[t] = inv_sum[rowBase + t];

    const int ar = t >> 3, ac4 = (t & 7) * 4;  // i adds 64 rows

    f32x4 acc[4][4];
#pragma unroll
    for (int m = 0; m < 4; m++)
#pragma unroll
        for (int n = 0; n < 4; n++) acc[m][n] = (f32x4){0.f, 0.f, 0.f, 0.f};

    // prologue: prefetch tile 0
    f32x4 pa[2];
    u16x8 pb[2];
#pragma unroll
    for (int i = 0; i < 2; i++) {
        int row = ar + i * 64;
        pa[i] = *reinterpret_cast<const f32x4*>(attn + (rowBase + row) * TKn + kbase + ac4);
    }
#pragma unroll
    for (int i = 0; i < 2; i++) {
        int f = i * 512 + t;
        int row = f >> 2, c8 = (f & 3) * 8;
        pb[i] = *reinterpret_cast<const u16x8*>(
            ebt + (size_t)(b * DOUTn + row) * TKn + kbase + c8);
    }
    __syncthreads();  // sInv ready

    const int NIT = KCH / 32;  // 16
    for (int it = 0; it < NIT; it++) {
        const int cur = it & 1;
        const int ks = it * 32;
        // ---- commit tile it ----
#pragma unroll
        for (int i = 0; i < 2; i++) {
            int row = ar + i * 64;
            f32x4 v = pa[i] * sInv[row];
            *reinterpret_cast<f32x4*>(attn + (rowBase + row) * TKn + kbase + ks + ac4) = v;
            u16x4 hv;
            hv[0] = __builtin_bit_cast(u16, (_Float16)v[0]);
            hv[1] = __builtin_bit_cast(u16, (_Float16)v[1]);
            hv[2] = __builtin_bit_cast(u16, (_Float16)v[2]);
            hv[3] = __builtin_bit_cast(u16, (_Float16)v[3]);
            *reinterpret_cast<u16x4*>(&sA[cur][row][ac4]) = hv;
        }
#pragma unroll
        for (int i = 0; i < 2; i++) {
            int f = i * 512 + t;
            int row = f >> 2, c8 = (f & 3) * 8;
            st8(&sB[cur][row][c8], pb[i]);
        }
        // ---- raw barrier (LDS visibility only) ----
        asm volatile("s_waitcnt lgkmcnt(0)" ::: "memory");
        __builtin_amdgcn_s_barrier();
        asm volatile("" ::: "memory");
        // ---- prefetch tile it+1 ----
        if (it + 1 < NIT) {
            int ksn = ks + 32;
#pragma unroll
            for (int i = 0; i < 2; i++) {
                int row = ar + i * 64;
                pa[i] = *reinterpret_cast<const f32x4*>(
                    attn + (rowBase + row) * TKn + kbase + ksn + ac4);
            }
#pragma unroll
            for (int i = 0; i < 2; i++) {
                int f = i * 512 + t;
                int row = f >> 2, c8 = (f & 3) * 8;
                pb[i] = *reinterpret_cast<const u16x8*>(
                    ebt + (size_t)(b * DOUTn + row) * TKn + kbase + ksn + c8);
            }
        }
        // ---- compute: 16 MFMA per wave ----
        half8 a[4], bb[4];
#pragma unroll
        for (int m = 0; m < 4; m++) a[m] = ld8h(&sA[cur][wr * 64 + m * 16 + lr][kg8]);
#pragma unroll
        for (int n = 0; n < 4; n++) bb[n] = ld8h(&sB[cur][wc * 64 + n * 16 + lr][kg8]);
#pragma unroll
        for (int m = 0; m < 4; m++)
#pragma unroll
            for (int n = 0; n < 4; n++)
                acc[m][n] = __builtin_amdgcn_mfma_f32_16x16x32_f16(a[m], bb[n], acc[m][n], 0, 0, 0);
    }
    // epilogue: partial[kc][row][col]
#pragma unroll
    for (int m = 0; m < 4; m++) {
#pragma unroll
        for (int n = 0; n < 4; n++) {
            int col = wc * 64 + n * 16 + lr;
#pragma unroll
            for (int r = 0; r < 4; r++) {
                size_t grow = rowBase + wr * 64 + m * 16 + g * 4 + r;
                partial[((size_t)kc * NROWS + grow) * DOUTn + col] = acc[m][n][r];
            }
        }
    }
}

// ---------------------------------------------------------------------------
// Kernel 6: out = sum of 8 partials
// ---------------------------------------------------------------------------
__global__ __launch_bounds__(256) void k_reduce(const float* __restrict__ partial,
                                                float* __restrict__ out) {
    const size_t stride = (size_t)NROWS * DOUTn;
    size_t i = ((size_t)blockIdx.x * 256 + threadIdx.x) * 4;
    f32x4 s = (f32x4){0.f, 0.f, 0.f, 0.f};
#pragma unroll
    for (int kc = 0; kc < NKC; kc++)
        s += *reinterpret_cast<const f32x4*>(partial + kc * stride + i);
    *reinterpret_cast<f32x4*>(out + i) = s;
}

// ---------------------------------------------------------------------------
extern "C" void kernel_launch(void* const* d_in, const int* in_sizes, int n_in,
                              void* d_out, int out_size, void* d_ws, size_t ws_size,
                              hipStream_t stream) {
    const float* dec = (const float*)d_in[0];
    const float* emb = (const float*)d_in[1];
    const int* emask = (const int*)d_in[2];
    const float* W = (const float*)d_in[3];
    const float* bias = (const float*)d_in[4];

    float* out = (float*)d_out;
    float* attn = out + (size_t)NROWS * DOUTn;

    char* wsb = (char*)d_ws;
    u16* ds_hi = (u16*)wsb;
    wsb += (size_t)NROWS * DOUTn * 2;
    u16* ds_lo = (u16*)wsb;
    wsb += (size_t)NROWS * DOUTn * 2;
    _Float16* embT = (_Float16*)wsb;
    wsb += (size_t)NB * DOUTn * TKn * 2;
    float* inv_sum = (float*)wsb;
    wsb += (size_t)NROWS * 4;
    float* partsum = (float*)wsb;
    wsb += (size_t)NKB * NROWS * 4;
    // union region: { ehi(16.8MB) + elo(16.8MB) } before PV, partial(67MB) after.
    // ehi/elo are dead once k_scores_exp completes; k_pv8's partial writes may
    // overwrite them.
    u16* ehi = (u16*)wsb;
    u16* elo = ehi + (size_t)NB * TKn * DOUTn;
    float* partial = (float*)wsb;

    k_embT<<<dim3(TKn / 64, DOUTn / 64, NB), 256, 0, stream>>>(emb, embT, ehi, elo);
    k_linear<<<dim3(NROWS / 128, DOUTn / 64), 256, 0, stream>>>(dec, W, bias, ds_hi, ds_lo);
    k_scores_exp<<<dim3(TQn / 128, NKB, NB), 256, 0, stream>>>(ds_hi, ds_lo, ehi, elo, emask, attn, partsum);
    k_rowsum<<<dim3(NROWS / 256), 256, 0, stream>>>(partsum, inv_sum);
    k_pv8<<<dim3(512), 512, 0, stream>>>(attn, embT, inv_sum, partial);
    k_reduce<<<dim3((NROWS * DOUTn / 4) / 256), 256, 0, stream>>>(partial, out);
}